// Round 5
// baseline (30.728 us; speedup 1.0000x reference)
//
#include <hip/hip_runtime.h>
#include <hip/hip_bf16.h>

#define TT 8
#define NN 1536
#define BB 192

typedef __attribute__((ext_vector_type(8))) short short8;
typedef __attribute__((ext_vector_type(4))) float f32x4;

static __device__ inline short f2bf_bits(float x) {
  __hip_bfloat16 b = __float2bfloat16(x);
  return *reinterpret_cast<short*>(&b);
}
static __device__ inline float sigm(float x) {
  return 1.f / (1.f + __expf(-x));
}
static __device__ inline float tanh_fast(float x) {
  return 2.f / (1.f + __expf(-2.f * x)) - 1.f;
}
static __device__ inline unsigned int imagic(int s) {
  return 0xA11C0DEu ^ (unsigned int)s;
}
static __device__ inline unsigned int dmagic(int b) {
  return 0xD00DF00Du ^ (unsigned int)(b * 2654435761u);
}

// Single dispatch: 192 blocks = (96 j-tiles x 2 robot-halves) x 512 threads.
// Producer part identical to R4's pair_partial_kernel, but partial maxes go
// through device-scope atomicMax on float-as-uint (all values >= 0 -> uint
// order == float order; order-independent -> deterministic).
// Poisoned-workspace protocol (no memset dispatch needed):
//   blocks 168..191: atomicExch pooled cells to 0 at entry, publish init-flags
//   all blocks:      poll init-flags once before pooling atomics
//   all blocks:      __syncthreads (drains vmcnt -> atomics at coherence
//                    point), then publish doneflag[bid] = dmagic(bid)
//   blocks 0..23:    poll all 192 distinct-magic doneflags, then fusion MLP
//                    for 8 robots each (atomic reads -> coherent).
// Deadlock-safety: every block writes its flag unconditionally; 192 blocks
// <= 256 CUs so all are co-resident; spins have bounded safety valves
// (wrong-result-visible, never hang). NO grid.sync / threadfence (R1 lesson).
__global__ __launch_bounds__(512) void mono_kernel(
    const float* __restrict__ traj_rel, const float* __restrict__ obs_traj_pos,
    const float* __restrict__ W_he, const float* __restrict__ b_he,
    const float* __restrict__ W_ih, const float* __restrict__ W_hh,
    const float* __restrict__ b_ih, const float* __restrict__ b_hh,
    const float* __restrict__ W_sp, const float* __restrict__ b_sp,
    const float* __restrict__ W_p1, const float* __restrict__ b_p1,
    const int* __restrict__ neigh, const int* __restrict__ robot_idx,
    const float* __restrict__ W_p2, const float* __restrict__ b_p2,
    const float* __restrict__ r_goal, const float* __restrict__ r_pose,
    const float* __restrict__ action,
    const float* __restrict__ W_emb, const float* __restrict__ b_emb,
    const float* __restrict__ W_fc, const float* __restrict__ b_fc,
    unsigned int* pooled_enc, unsigned int* initflag, unsigned int* doneflag,
    float* __restrict__ out) {
  const int bid = blockIdx.x;
  const int jt = bid >> 1;
  const int half = bid & 1;
  const int j0 = jt * 16;
  const int r0 = half * 96;
  const int tid = threadIdx.x;
  const int wave = tid >> 6;     // 0..7
  const int l = tid & 63;
  const int n = l & 15;
  const int grp = l >> 4;        // 0..3

  __shared__ float dS[16][68];    // +4 pad: break 256B row stride
  __shared__ float aS[96][64];
  __shared__ float maskS[96][16];

  // ---- init slice (blocks 168..191): zero pooled cells, publish init flag
  if (bid >= 168) {
    int s = bid - 168;           // 0..23, slice of 128 of the 3072 cells
    if (tid < 128) atomicExch(&pooled_enc[s * 128 + tid], 0u);
    __syncthreads();             // drain -> exchs at coherence point
    if (tid == 0) atomicExch(&initflag[s], imagic(s));
  }

  if (wave < 4) {
    // ---- LSTM for agents j0 + wave*4 .. +3 (folded math, reg/shfl only) ----
    const int u = n;             // hidden unit
    const int agent = j0 + wave * 4 + grp;
    const int gbase = l & 48;

    float whh[4][16];
    #pragma unroll
    for (int g = 0; g < 4; ++g)
      #pragma unroll
      for (int k = 0; k < 16; ++k)
        whh[g][k] = W_hh[k * 64 + g * 16 + u];

    float G0[4], G1[4], Cc[4];
    #pragma unroll
    for (int g = 0; g < 4; ++g) {
      float a0 = 0.f, a1 = 0.f, c0 = b_ih[g * 16 + u] + b_hh[g * 16 + u];
      #pragma unroll
      for (int e = 0; e < 16; ++e) {
        float wih = W_ih[e * 64 + g * 16 + u];
        a0 = fmaf(W_he[e], wih, a0);
        a1 = fmaf(W_he[16 + e], wih, a1);
        c0 = fmaf(b_he[e], wih, c0);
      }
      G0[g] = a0; G1[g] = a1; Cc[g] = c0;
    }

    float r0s[TT], r1s[TT];
    #pragma unroll
    for (int t = 0; t < TT; ++t) {
      r0s[t] = traj_rel[(t * NN + agent) * 2 + 0];
      r1s[t] = traj_rel[(t * NN + agent) * 2 + 1];
    }

    float h = 0.f, c = 0.f;
    #pragma unroll
    for (int t = 0; t < TT; ++t) {
      float ga[4], gb[4];
      #pragma unroll
      for (int g = 0; g < 4; ++g) {
        ga[g] = fmaf(r0s[t], G0[g], fmaf(r1s[t], G1[g], Cc[g]));
        gb[g] = 0.f;
      }
      #pragma unroll
      for (int k = 0; k < 8; ++k) {
        float hk = __shfl(h, gbase + k);
        ga[0] = fmaf(hk, whh[0][k], ga[0]);
        ga[1] = fmaf(hk, whh[1][k], ga[1]);
        ga[2] = fmaf(hk, whh[2][k], ga[2]);
        ga[3] = fmaf(hk, whh[3][k], ga[3]);
      }
      #pragma unroll
      for (int k = 8; k < 16; ++k) {
        float hk = __shfl(h, gbase + k);
        gb[0] = fmaf(hk, whh[0][k], gb[0]);
        gb[1] = fmaf(hk, whh[1][k], gb[1]);
        gb[2] = fmaf(hk, whh[2][k], gb[2]);
        gb[3] = fmaf(hk, whh[3][k], gb[3]);
      }
      float g0 = ga[0] + gb[0];
      float g1 = ga[1] + gb[1];
      float g2 = ga[2] + gb[2];
      float g3 = ga[3] + gb[3];
      float si = sigm(g0), sf = sigm(g1), so = sigm(g3);
      float tg = tanh_fast(g2);
      c = sf * c + si * tg;
      h = so * tanh_fast(c);
    }

    // ---- d tail: thread owns column m = l, wave's 4 agents -> dS ----
    const int m = l;
    float M0 = 0.f, M1 = 0.f, Cm = b_p1[m];
    #pragma unroll
    for (int e = 0; e < 16; ++e) {
      float wp = W_p1[e * 64 + m];
      M0 = fmaf(W_sp[e], wp, M0);
      M1 = fmaf(W_sp[16 + e], wp, M1);
      Cm = fmaf(b_sp[e], wp, Cm);
    }
    float w1h[16];
    #pragma unroll
    for (int k = 0; k < 16; ++k) w1h[k] = W_p1[(16 + k) * 64 + m];

    #pragma unroll
    for (int q = 0; q < 4; ++q) {
      int j = j0 + wave * 4 + q;
      float px = obs_traj_pos[((TT - 1) * NN + j) * 2 + 0];
      float py = obs_traj_pos[((TT - 1) * NN + j) * 2 + 1];
      float a = fmaf(px, M0, py * M1);
      float dacc = Cm - a;
      #pragma unroll
      for (int k = 0; k < 16; ++k) {
        float hk = __shfl(h, q * 16 + k);
        dacc = fmaf(hk, w1h[k], dacc);
      }
      dS[wave * 4 + q][m] = dacc;
    }
  } else {
    // ---- concurrent: a-rows + mask for this half's 96 robots ----
    const int w = wave - 4;      // 0..3
    float M0 = 0.f, M1 = 0.f;
    #pragma unroll
    for (int e = 0; e < 16; ++e) {
      float wp = W_p1[e * 64 + l];
      M0 = fmaf(W_sp[e], wp, M0);
      M1 = fmaf(W_sp[16 + e], wp, M1);
    }
    #pragma unroll
    for (int p = 0; p < 24; ++p) {
      int rr = w * 24 + p;
      int ir = robot_idx[r0 + rr];
      float px = obs_traj_pos[((TT - 1) * NN + ir) * 2 + 0];
      float py = obs_traj_pos[((TT - 1) * NN + ir) * 2 + 1];
      aS[rr][l] = fmaf(px, M0, py * M1);
    }
    #pragma unroll
    for (int p = 0; p < 6; ++p) {
      int rr = w * 24 + p * 4 + grp;
      int ir = robot_idx[r0 + rr];
      maskS[rr][n] = (neigh[ir * NN + j0 + n] > 0) ? 1.f : 0.f;
    }
  }

  // every wave: W_p2 fragments (lane-dependent, phase-independent)
  short8 bfrag0, bfrag1;
  #pragma unroll
  for (int e = 0; e < 8; ++e) {
    bfrag0[e] = f2bf_bits(W_p2[(grp * 8 + e) * 16 + n]);
    bfrag1[e] = f2bf_bits(W_p2[(32 + grp * 8 + e) * 16 + n]);
  }
  const float b2val = b_p2[n];
  __syncthreads();

  // d fragment for this lane's pair-row n (robot-invariant, hoisted)
  float d0[8], d1[8];
  #pragma unroll
  for (int e = 0; e < 8; ++e) {
    d0[e] = dS[n][grp * 8 + e];
    d1[e] = dS[n][32 + grp * 8 + e];
  }

  // ---- init-flag poll (one round in practice; init finished ~1.5us ago) ----
  for (int it = 0; ; ++it) {
    int ok = 1;
    if (tid < 24) ok = (atomicAdd(&initflag[tid], 0u) == imagic(tid)) ? 1 : 0;
    if (__syncthreads_count(ok) == 512) break;
    if (it > (1 << 17)) break;   // safety valve: fail visibly, never hang
    __builtin_amdgcn_s_sleep(1);
  }

  // ---- pairwise: 12 robots per wave, partial max via device atomicMax ----
  for (int p = 0; p < 12; ++p) {
    const int rr = wave * 12 + p;
    float ar0[8], ar1[8];        // LDS broadcast (same addr per 16-lane grp)
    #pragma unroll
    for (int e = 0; e < 8; ++e) {
      ar0[e] = aS[rr][grp * 8 + e];
      ar1[e] = aS[rr][32 + grp * 8 + e];
    }
    short8 af0, af1;
    #pragma unroll
    for (int e = 0; e < 8; ++e) {
      af0[e] = f2bf_bits(fmaxf(ar0[e] + d0[e], 0.f));
      af1[e] = f2bf_bits(fmaxf(ar1[e] + d1[e], 0.f));
    }
    f32x4 acc = {0.f, 0.f, 0.f, 0.f};
    acc = __builtin_amdgcn_mfma_f32_16x16x32_bf16(af0, bfrag0, acc, 0, 0, 0);
    acc = __builtin_amdgcn_mfma_f32_16x16x32_bf16(af1, bfrag1, acc, 0, 0, 0);

    float vr = 0.f;
    #pragma unroll
    for (int q = 0; q < 4; ++q) {
      float v = fmaxf(acc[q] + b2val, 0.f) * maskS[rr][grp * 4 + q];
      vr = fmaxf(vr, v);
    }
    vr = fmaxf(vr, __shfl_xor(vr, 16));
    vr = fmaxf(vr, __shfl_xor(vr, 32));
    // v >= 0 -> float order == uint order; init 0 is the identity
    if (l < 16)
      atomicMax(&pooled_enc[(r0 + rr) * 16 + n], __float_as_uint(vr));
  }

  // barrier drains vmcnt -> this block's atomics are at the coherence point
  __syncthreads();
  if (tid == 0) atomicExch(&doneflag[bid], dmagic(bid));

  if (bid >= 24) return;

  // ---- fusion blocks 0..23: wait for all 192 producer blocks ----
  for (int it = 0; ; ++it) {
    int ok = 1;
    if (tid < 192) ok = (atomicAdd(&doneflag[tid], 0u) == dmagic(tid)) ? 1 : 0;
    if (__syncthreads_count(ok) == 512) break;
    if (it > (1 << 17)) break;   // safety valve
    __builtin_amdgcn_s_sleep(1);
  }

  // ---- fusion MLP for robots rbase..rbase+7 ----
  __shared__ float fuseS[8][37];
  const int rbase = bid * 8;
  if (tid < 128) {
    int rb = tid >> 4, m = tid & 15;
    int br = rbase + rb;
    unsigned int e = atomicAdd(&pooled_enc[br * 16 + m], 0u);  // coherent read
    float pv = __uint_as_float(e);
    int i = robot_idx[br];
    float px = obs_traj_pos[((TT - 1) * NN + i) * 2 + 0];
    float py = obs_traj_pos[((TT - 1) * NN + i) * 2 + 1];
    float s0 = r_goal[br * 2 + 0] - px;
    float s1 = r_goal[br * 2 + 1] - py;
    float s2 = action[br * 2 + 0];
    float s3 = action[br * 2 + 1];
    float v = b_emb[m];
    v = fmaf(s0, W_emb[m], v);
    v = fmaf(s1, W_emb[16 + m], v);
    v = fmaf(s2, W_emb[32 + m], v);
    v = fmaf(s3, W_emb[48 + m], v);
    fuseS[rb][m] = fmaxf(v, 0.f);
    fuseS[rb][16 + m] = pv;
  } else if (tid < 168) {
    int t2 = tid - 128, rb = t2 / 5, p = t2 % 5;
    fuseS[rb][32 + p] = r_pose[(rbase + rb) * 5 + p];
  }
  __syncthreads();

  {
    int rb = tid >> 6;           // 0..7 (one wave per robot)
    int c0 = tid & 63;
    #pragma unroll
    for (int q = 0; q < 4; ++q) {
      int c = c0 + q * 64;
      float acc = b_fc[c];
      #pragma unroll
      for (int k = 0; k < 37; ++k)
        acc = fmaf(fuseS[rb][k], W_fc[k * 256 + c], acc);
      out[(rbase + rb) * 256 + c] = fmaxf(acc, 0.f);
    }
  }
}

extern "C" void kernel_launch(void* const* d_in, const int* in_sizes, int n_in,
                              void* d_out, int out_size, void* d_ws, size_t ws_size,
                              hipStream_t stream) {
  const float* obs_traj_pos = (const float*)d_in[0];
  const float* traj_rel     = (const float*)d_in[1];
  const int*   neigh_index  = (const int*)d_in[2];
  const int*   robot_idx    = (const int*)d_in[3];
  const float* r_goal       = (const float*)d_in[4];
  const float* r_pose       = (const float*)d_in[5];
  const float* action       = (const float*)d_in[6];
  const float* W_he = (const float*)d_in[7];
  const float* b_he = (const float*)d_in[8];
  const float* W_ih = (const float*)d_in[9];
  const float* W_hh = (const float*)d_in[10];
  const float* b_ih = (const float*)d_in[11];
  const float* b_hh = (const float*)d_in[12];
  const float* W_sp = (const float*)d_in[13];
  const float* b_sp = (const float*)d_in[14];
  const float* W_p1 = (const float*)d_in[15];
  const float* b_p1 = (const float*)d_in[16];
  const float* W_p2 = (const float*)d_in[17];
  const float* b_p2 = (const float*)d_in[18];
  const float* W_emb = (const float*)d_in[19];
  const float* b_emb = (const float*)d_in[20];
  const float* W_fc  = (const float*)d_in[21];
  const float* b_fc  = (const float*)d_in[22];
  float* out = (float*)d_out;

  // ws protocol buffers (poison-tolerant by construction):
  //   pooled_enc[192*16] u32, initflag[24] u32, doneflag[192] u32
  unsigned int* pooled_enc = (unsigned int*)d_ws;
  unsigned int* initflag   = pooled_enc + 4096;
  unsigned int* doneflag   = pooled_enc + 4352;

  mono_kernel<<<192, 512, 0, stream>>>(
      traj_rel, obs_traj_pos, W_he, b_he, W_ih, W_hh, b_ih, b_hh,
      W_sp, b_sp, W_p1, b_p1, neigh_index, robot_idx, W_p2, b_p2,
      r_goal, r_pose, action, W_emb, b_emb, W_fc, b_fc,
      pooled_enc, initflag, doneflag, out);
}

// Round 6
// 19.331 us; speedup vs baseline: 1.5896x; 1.5896x over previous
//
#include <hip/hip_runtime.h>
#include <hip/hip_bf16.h>

#define TT 8
#define NN 1536
#define BB 192

typedef __attribute__((ext_vector_type(8))) short short8;
typedef __attribute__((ext_vector_type(4))) float f32x4;

static __device__ inline short f2bf_bits(float x) {
  __hip_bfloat16 b = __float2bfloat16(x);
  return *reinterpret_cast<short*>(&b);
}
static __device__ inline float sigm(float x) {
  return 1.f / (1.f + __expf(-x));
}
static __device__ inline float tanh_fast(float x) {
  return 2.f / (1.f + __expf(-2.f * x)) - 1.f;
}

// ---------------- k_a: j-tile pairwise partial-pool ------------------------
// 192 blocks = (96 j-tiles x 2 robot-halves) x 512 threads (8 waves).
// Waves 0-3: LSTM for the tile's 16 agents -> d rows in LDS (no global dMat).
// Waves 4-7 (concurrent): a-rows for 96 robots + neighbor mask -> LDS.
// After one barrier: each wave does 12 robots x (16 j x 64 K x 16 out) via
// 2 MFMAs, masked max over the tile's 16 j's -> part[jt][robot][16].
__global__ __launch_bounds__(512) void pair_partial_kernel(
    const float* __restrict__ traj_rel, const float* __restrict__ obs_traj_pos,
    const float* __restrict__ W_he, const float* __restrict__ b_he,
    const float* __restrict__ W_ih, const float* __restrict__ W_hh,
    const float* __restrict__ b_ih, const float* __restrict__ b_hh,
    const float* __restrict__ W_sp, const float* __restrict__ b_sp,
    const float* __restrict__ W_p1, const float* __restrict__ b_p1,
    const int* __restrict__ neigh, const int* __restrict__ robot_idx,
    const float* __restrict__ W_p2, const float* __restrict__ b_p2,
    float* __restrict__ part) {
  const int jt = blockIdx.x >> 1;
  const int half = blockIdx.x & 1;
  const int j0 = jt * 16;
  const int r0 = half * 96;
  const int tid = threadIdx.x;
  const int wave = tid >> 6;     // 0..7
  const int l = tid & 63;
  const int n = l & 15;
  const int grp = l >> 4;        // 0..3

  __shared__ float dS[16][68];    // +4 pad: break 256B row stride
  __shared__ float aS[96][64];
  __shared__ float maskS[96][16];

  if (wave < 4) {
    // ---- LSTM for agents j0 + wave*4 .. +3 (folded math, reg/shfl only) ----
    const int u = n;             // hidden unit
    const int agent = j0 + wave * 4 + grp;
    const int gbase = l & 48;

    float whh[4][16];
    #pragma unroll
    for (int g = 0; g < 4; ++g)
      #pragma unroll
      for (int k = 0; k < 16; ++k)
        whh[g][k] = W_hh[k * 64 + g * 16 + u];

    float G0[4], G1[4], Cc[4];
    #pragma unroll
    for (int g = 0; g < 4; ++g) {
      float a0 = 0.f, a1 = 0.f, c0 = b_ih[g * 16 + u] + b_hh[g * 16 + u];
      #pragma unroll
      for (int e = 0; e < 16; ++e) {
        float wih = W_ih[e * 64 + g * 16 + u];
        a0 = fmaf(W_he[e], wih, a0);
        a1 = fmaf(W_he[16 + e], wih, a1);
        c0 = fmaf(b_he[e], wih, c0);
      }
      G0[g] = a0; G1[g] = a1; Cc[g] = c0;
    }

    float r0s[TT], r1s[TT];
    #pragma unroll
    for (int t = 0; t < TT; ++t) {
      r0s[t] = traj_rel[(t * NN + agent) * 2 + 0];
      r1s[t] = traj_rel[(t * NN + agent) * 2 + 1];
    }

    float h = 0.f, c = 0.f;
    #pragma unroll
    for (int t = 0; t < TT; ++t) {
      float ga[4], gb[4];
      #pragma unroll
      for (int g = 0; g < 4; ++g) {
        ga[g] = fmaf(r0s[t], G0[g], fmaf(r1s[t], G1[g], Cc[g]));
        gb[g] = 0.f;
      }
      #pragma unroll
      for (int k = 0; k < 8; ++k) {
        float hk = __shfl(h, gbase + k);
        ga[0] = fmaf(hk, whh[0][k], ga[0]);
        ga[1] = fmaf(hk, whh[1][k], ga[1]);
        ga[2] = fmaf(hk, whh[2][k], ga[2]);
        ga[3] = fmaf(hk, whh[3][k], ga[3]);
      }
      #pragma unroll
      for (int k = 8; k < 16; ++k) {
        float hk = __shfl(h, gbase + k);
        gb[0] = fmaf(hk, whh[0][k], gb[0]);
        gb[1] = fmaf(hk, whh[1][k], gb[1]);
        gb[2] = fmaf(hk, whh[2][k], gb[2]);
        gb[3] = fmaf(hk, whh[3][k], gb[3]);
      }
      float g0 = ga[0] + gb[0];
      float g1 = ga[1] + gb[1];
      float g2 = ga[2] + gb[2];
      float g3 = ga[3] + gb[3];
      float si = sigm(g0), sf = sigm(g1), so = sigm(g3);
      float tg = tanh_fast(g2);
      c = sf * c + si * tg;
      h = so * tanh_fast(c);
    }

    // ---- d tail: thread owns column m = l, wave's 4 agents -> dS ----
    const int m = l;
    float M0 = 0.f, M1 = 0.f, Cm = b_p1[m];
    #pragma unroll
    for (int e = 0; e < 16; ++e) {
      float wp = W_p1[e * 64 + m];
      M0 = fmaf(W_sp[e], wp, M0);
      M1 = fmaf(W_sp[16 + e], wp, M1);
      Cm = fmaf(b_sp[e], wp, Cm);
    }
    float w1h[16];
    #pragma unroll
    for (int k = 0; k < 16; ++k) w1h[k] = W_p1[(16 + k) * 64 + m];

    #pragma unroll
    for (int q = 0; q < 4; ++q) {
      int j = j0 + wave * 4 + q;
      float px = obs_traj_pos[((TT - 1) * NN + j) * 2 + 0];
      float py = obs_traj_pos[((TT - 1) * NN + j) * 2 + 1];
      float a = fmaf(px, M0, py * M1);
      float dacc = Cm - a;
      #pragma unroll
      for (int k = 0; k < 16; ++k) {
        float hk = __shfl(h, q * 16 + k);
        dacc = fmaf(hk, w1h[k], dacc);
      }
      dS[wave * 4 + q][m] = dacc;
    }
  } else {
    // ---- concurrent: a-rows + mask for this half's 96 robots ----
    const int w = wave - 4;      // 0..3
    float M0 = 0.f, M1 = 0.f;
    #pragma unroll
    for (int e = 0; e < 16; ++e) {
      float wp = W_p1[e * 64 + l];
      M0 = fmaf(W_sp[e], wp, M0);
      M1 = fmaf(W_sp[16 + e], wp, M1);
    }
    #pragma unroll
    for (int p = 0; p < 24; ++p) {
      int rr = w * 24 + p;
      int ir = robot_idx[r0 + rr];
      float px = obs_traj_pos[((TT - 1) * NN + ir) * 2 + 0];
      float py = obs_traj_pos[((TT - 1) * NN + ir) * 2 + 1];
      aS[rr][l] = fmaf(px, M0, py * M1);
    }
    #pragma unroll
    for (int p = 0; p < 6; ++p) {
      int rr = w * 24 + p * 4 + grp;
      int ir = robot_idx[r0 + rr];
      maskS[rr][n] = (neigh[ir * NN + j0 + n] > 0) ? 1.f : 0.f;
    }
  }

  // every wave: W_p2 fragments (lane-dependent, phase-independent)
  short8 bfrag0, bfrag1;
  #pragma unroll
  for (int e = 0; e < 8; ++e) {
    bfrag0[e] = f2bf_bits(W_p2[(grp * 8 + e) * 16 + n]);
    bfrag1[e] = f2bf_bits(W_p2[(32 + grp * 8 + e) * 16 + n]);
  }
  const float b2val = b_p2[n];
  __syncthreads();

  // d fragment for this lane's pair-row n (robot-invariant, hoisted)
  float d0[8], d1[8];
  #pragma unroll
  for (int e = 0; e < 8; ++e) {
    d0[e] = dS[n][grp * 8 + e];
    d1[e] = dS[n][32 + grp * 8 + e];
  }

  // ---- pairwise: 12 robots per wave ----
  for (int p = 0; p < 12; ++p) {
    const int rr = wave * 12 + p;
    float ar0[8], ar1[8];        // LDS broadcast (same addr per 16-lane grp)
    #pragma unroll
    for (int e = 0; e < 8; ++e) {
      ar0[e] = aS[rr][grp * 8 + e];
      ar1[e] = aS[rr][32 + grp * 8 + e];
    }
    short8 af0, af1;
    #pragma unroll
    for (int e = 0; e < 8; ++e) {
      af0[e] = f2bf_bits(fmaxf(ar0[e] + d0[e], 0.f));
      af1[e] = f2bf_bits(fmaxf(ar1[e] + d1[e], 0.f));
    }
    f32x4 acc = {0.f, 0.f, 0.f, 0.f};
    acc = __builtin_amdgcn_mfma_f32_16x16x32_bf16(af0, bfrag0, acc, 0, 0, 0);
    acc = __builtin_amdgcn_mfma_f32_16x16x32_bf16(af1, bfrag1, acc, 0, 0, 0);

    float vr = 0.f;
    #pragma unroll
    for (int q = 0; q < 4; ++q) {
      float v = fmaxf(acc[q] + b2val, 0.f) * maskS[rr][grp * 4 + q];
      vr = fmaxf(vr, v);
    }
    vr = fmaxf(vr, __shfl_xor(vr, 16));
    vr = fmaxf(vr, __shfl_xor(vr, 32));
    if (l < 16) part[(jt * 192 + r0 + rr) * 16 + n] = vr;
  }
}

// ---------------- k_b: 96-way max reduce + fusion MLP ----------------------
// 192 blocks x 256 threads.
__global__ __launch_bounds__(256) void reduce_fusion_kernel(
    const float* __restrict__ part,
    const int* __restrict__ robot_idx,
    const float* __restrict__ obs_traj_pos,
    const float* __restrict__ r_goal, const float* __restrict__ r_pose,
    const float* __restrict__ action,
    const float* __restrict__ W_emb, const float* __restrict__ b_emb,
    const float* __restrict__ W_fc, const float* __restrict__ b_fc,
    float* __restrict__ out) {
  const int b = blockIdx.x;
  const int tid = threadIdx.x;

  __shared__ float redB[16][16];
  __shared__ float fuse[37];

  {
    const int m = tid & 15;
    const int ch = tid >> 4;     // 0..15
    float v = 0.f;
    #pragma unroll
    for (int s = 0; s < 6; ++s) {
      int jtt = ch + s * 16;     // covers 0..95
      v = fmaxf(v, part[(jtt * 192 + b) * 16 + m]);
    }
    redB[ch][m] = v;
  }
  __syncthreads();

  if (tid < 16) {
    int i = robot_idx[b];
    float px = obs_traj_pos[((TT - 1) * NN + i) * 2 + 0];
    float py = obs_traj_pos[((TT - 1) * NN + i) * 2 + 1];
    float s0 = r_goal[b * 2 + 0] - px;
    float s1 = r_goal[b * 2 + 1] - py;
    float s2 = action[b * 2 + 0];
    float s3 = action[b * 2 + 1];
    float v = b_emb[tid];
    v = fmaf(s0, W_emb[tid], v);
    v = fmaf(s1, W_emb[16 + tid], v);
    v = fmaf(s2, W_emb[32 + tid], v);
    v = fmaf(s3, W_emb[48 + tid], v);
    fuse[tid] = fmaxf(v, 0.f);
  } else if (tid < 32) {
    int m2 = tid - 16;
    float v = redB[0][m2];
    #pragma unroll
    for (int ch = 1; ch < 16; ++ch) v = fmaxf(v, redB[ch][m2]);
    fuse[tid] = v;
  } else if (tid < 37) {
    fuse[tid] = r_pose[b * 5 + (tid - 32)];
  }
  __syncthreads();

  float acc = b_fc[tid];
  #pragma unroll
  for (int k = 0; k < 37; ++k) acc = fmaf(fuse[k], W_fc[k * 256 + tid], acc);
  out[b * 256 + tid] = fmaxf(acc, 0.f);
}

extern "C" void kernel_launch(void* const* d_in, const int* in_sizes, int n_in,
                              void* d_out, int out_size, void* d_ws, size_t ws_size,
                              hipStream_t stream) {
  const float* obs_traj_pos = (const float*)d_in[0];
  const float* traj_rel     = (const float*)d_in[1];
  const int*   neigh_index  = (const int*)d_in[2];
  const int*   robot_idx    = (const int*)d_in[3];
  const float* r_goal       = (const float*)d_in[4];
  const float* r_pose       = (const float*)d_in[5];
  const float* action       = (const float*)d_in[6];
  const float* W_he = (const float*)d_in[7];
  const float* b_he = (const float*)d_in[8];
  const float* W_ih = (const float*)d_in[9];
  const float* W_hh = (const float*)d_in[10];
  const float* b_ih = (const float*)d_in[11];
  const float* b_hh = (const float*)d_in[12];
  const float* W_sp = (const float*)d_in[13];
  const float* b_sp = (const float*)d_in[14];
  const float* W_p1 = (const float*)d_in[15];
  const float* b_p1 = (const float*)d_in[16];
  const float* W_p2 = (const float*)d_in[17];
  const float* b_p2 = (const float*)d_in[18];
  const float* W_emb = (const float*)d_in[19];
  const float* b_emb = (const float*)d_in[20];
  const float* W_fc  = (const float*)d_in[21];
  const float* b_fc  = (const float*)d_in[22];
  float* out = (float*)d_out;

  // part[96][192][16] floats = 1.18 MB; fully overwritten every launch
  // (no zero-init needed -> poison-safe).
  float* part = (float*)d_ws;

  pair_partial_kernel<<<192, 512, 0, stream>>>(
      traj_rel, obs_traj_pos, W_he, b_he, W_ih, W_hh, b_ih, b_hh,
      W_sp, b_sp, W_p1, b_p1, neigh_index, robot_idx, W_p2, b_p2, part);
  reduce_fusion_kernel<<<BB, 256, 0, stream>>>(
      part, robot_idx, obs_traj_pos, r_goal, r_pose, action,
      W_emb, b_emb, W_fc, b_fc, out);
}